// Round 6
// baseline (1142.356 us; speedup 1.0000x reference)
//
#include <hip/hip_runtime.h>

#define USER_NUM 200000
#define ITEM_NUM 100000
#define N_NODES  300000   // USER_NUM + ITEM_NUM
#define EMB      64
#define N_EDGES  4800000
#define N_LAYERS 3

#define SCAN_CHUNK 2048   // elements per scan1 block (256 thr x 8)
#define SCAN_NB    ((N_NODES + SCAN_CHUNK - 1) / SCAN_CHUNK)  // 147

#define N_STRIPES     8                       // == XCD count
#define STRIPE_NODES  (N_NODES / N_STRIPES)   // 37500

// clang ext vector types for __builtin_nontemporal_load (HIP_vector_type is
// rejected by the builtin).
typedef int   iv4 __attribute__((ext_vector_type(4)));
typedef float fv4 __attribute__((ext_vector_type(4)));
typedef int   iv2 __attribute__((ext_vector_type(2)));

// ---------------- CSR build (runs every call) ------------------------------

// Histogram of src degrees: 4 edges/thread, vectorized nt loads.
__global__ __launch_bounds__(256) void hist_kernel(
    const int* __restrict__ esrc, int* __restrict__ cnt)
{
    int base = (blockIdx.x * 256 + threadIdx.x) * 4;
    if (base >= N_EDGES) return;
    if (base + 4 <= N_EDGES) {
        iv4 s4 = __builtin_nontemporal_load((const iv4*)(esrc + base));
        atomicAdd(&cnt[s4.x], 1);
        atomicAdd(&cnt[s4.y], 1);
        atomicAdd(&cnt[s4.z], 1);
        atomicAdd(&cnt[s4.w], 1);
    } else {
        for (int k = 0; k < 4 && base + k < N_EDGES; ++k)
            atomicAdd(&cnt[esrc[base + k]], 1);
    }
}

// Exclusive scan, stage 1: per-block scan of SCAN_CHUNK elements.
__global__ __launch_bounds__(256) void scan1_kernel(
    const int* __restrict__ cnt, int* __restrict__ rowptr,
    int* __restrict__ blockSums)
{
    __shared__ int lds[256];
    int base = blockIdx.x * SCAN_CHUNK + threadIdx.x * 8;
    int v[8];
    int s = 0;
    #pragma unroll
    for (int i = 0; i < 8; ++i) {
        int idx = base + i;
        v[i] = (idx < N_NODES) ? cnt[idx] : 0;
        s += v[i];
    }
    lds[threadIdx.x] = s;
    __syncthreads();
    for (int off = 1; off < 256; off <<= 1) {
        int t = (threadIdx.x >= off) ? lds[threadIdx.x - off] : 0;
        __syncthreads();
        lds[threadIdx.x] += t;
        __syncthreads();
    }
    int excl = (threadIdx.x == 0) ? 0 : lds[threadIdx.x - 1];
    if (threadIdx.x == 255) blockSums[blockIdx.x] = lds[255];
    int run = excl;
    #pragma unroll
    for (int i = 0; i < 8; ++i) {
        int idx = base + i;
        if (idx < N_NODES) rowptr[idx] = run;
        run += v[i];
    }
}

// Stage 2: exclusive-scan the (147) block sums in-place, single block.
__global__ __launch_bounds__(256) void scan2_kernel(int* __restrict__ blockSums, int nb)
{
    __shared__ int lds[256];
    int v = (threadIdx.x < nb) ? blockSums[threadIdx.x] : 0;
    lds[threadIdx.x] = v;
    __syncthreads();
    for (int off = 1; off < 256; off <<= 1) {
        int t = (threadIdx.x >= off) ? lds[threadIdx.x - off] : 0;
        __syncthreads();
        lds[threadIdx.x] += t;
        __syncthreads();
    }
    int excl = (threadIdx.x == 0) ? 0 : lds[threadIdx.x - 1];
    if (threadIdx.x < nb) blockSums[threadIdx.x] = excl;
}

// Stage 3: add block offsets; init scatter cursors; write rowptr[N] = E.
__global__ __launch_bounds__(256) void scan3_kernel(
    int* __restrict__ rowptr, int* __restrict__ cursor,
    const int* __restrict__ blockSums)
{
    int idx = blockIdx.x * blockDim.x + threadIdx.x;
    if (idx > N_NODES) return;
    if (idx == N_NODES) { rowptr[N_NODES] = N_EDGES; return; }
    int r = rowptr[idx] + blockSums[idx / SCAN_CHUNK];
    rowptr[idx] = r;
    cursor[idx] = r;
}

// XCD-pinned striped permute. Linear blocks map round-robin to XCDs, so
// stripe = blockIdx & 7 pins each src-stripe's CSR writes to ONE XCD's L2:
// 8B writes accumulate into full 64B lines before writeback. Edge reads are
// nontemporal (evict-first) so the 8x re-read stream doesn't evict the
// write lines. Correctness does not depend on the XCD mapping (speed only).
__global__ __launch_bounds__(256) void scatter_kernel(
    const int* __restrict__ esrc, const int* __restrict__ edst,
    const float* __restrict__ eval, int* __restrict__ cursor,
    int2* __restrict__ edges_s)
{
    int stripe = blockIdx.x & 7;
    int chunk  = blockIdx.x >> 3;
    int base   = chunk * 1024 + (int)threadIdx.x * 4;   // 4 edges/thread
    if (base >= N_EDGES) return;
    int lo = stripe * STRIPE_NODES;

    int s0, s1, s2, s3, d0, d1, d2, d3;
    float v0, v1, v2, v3;
    bool ok[4] = {true, true, true, true};
    if (base + 4 <= N_EDGES) {
        iv4 s4 = __builtin_nontemporal_load((const iv4*)(esrc + base));
        iv4 d4 = __builtin_nontemporal_load((const iv4*)(edst + base));
        fv4 v4 = __builtin_nontemporal_load((const fv4*)(eval + base));
        s0 = s4.x; s1 = s4.y; s2 = s4.z; s3 = s4.w;
        d0 = d4.x; d1 = d4.y; d2 = d4.z; d3 = d4.w;
        v0 = v4.x; v1 = v4.y; v2 = v4.z; v3 = v4.w;
    } else {
        s0 = s1 = s2 = s3 = 0; d0 = d1 = d2 = d3 = 0;
        v0 = v1 = v2 = v3 = 0.0f;
        int s[4], d[4]; float v[4];
        for (int k = 0; k < 4; ++k) {
            if (base + k < N_EDGES) {
                s[k] = esrc[base + k]; d[k] = edst[base + k]; v[k] = eval[base + k];
            } else { ok[k] = false; s[k] = 0; d[k] = 0; v[k] = 0.0f; }
        }
        s0 = s[0]; s1 = s[1]; s2 = s[2]; s3 = s[3];
        d0 = d[0]; d1 = d[1]; d2 = d[2]; d3 = d[3];
        v0 = v[0]; v1 = v[1]; v2 = v[2]; v3 = v[3];
    }

    if (ok[0] && (unsigned)(s0 - lo) < (unsigned)STRIPE_NODES) {
        int p = atomicAdd(&cursor[s0], 1);
        edges_s[p] = make_int2(d0, __float_as_int(v0));
    }
    if (ok[1] && (unsigned)(s1 - lo) < (unsigned)STRIPE_NODES) {
        int p = atomicAdd(&cursor[s1], 1);
        edges_s[p] = make_int2(d1, __float_as_int(v1));
    }
    if (ok[2] && (unsigned)(s2 - lo) < (unsigned)STRIPE_NODES) {
        int p = atomicAdd(&cursor[s2], 1);
        edges_s[p] = make_int2(d2, __float_as_int(v2));
    }
    if (ok[3] && (unsigned)(s3 - lo) < (unsigned)STRIPE_NODES) {
        int p = atomicAdd(&cursor[s3], 1);
        edges_s[p] = make_int2(d3, __float_as_int(v3));
    }
}

// ---------------- CSR SpMM: one wave per row, lane = column -----------------
// y[row][lane] = sum_e val_e * x[dst_e][lane];  acc += y/3 fused.
// Edge (dst,val) broadcast via readlane -> SGPRs; 16 gather loads in flight
// per group. edges_s is read nontemporal so the 38.4MB/layer edge stream
// doesn't evict gather rows (x) from L2.
__global__ __launch_bounds__(256) void spmm_csr(
    const int2*  __restrict__ edges_s,
    const int*   __restrict__ rowptr,
    const float* __restrict__ userp,
    const float* __restrict__ itemp,
    float*       __restrict__ y,
    float*       __restrict__ acc,
    int layer)
{
    int wid  = __builtin_amdgcn_readfirstlane(
                   (int)((blockIdx.x * blockDim.x + threadIdx.x) >> 6));
    int lane = threadIdx.x & 63;
    if (wid >= N_NODES) return;

    int start = rowptr[wid];
    int end   = rowptr[wid + 1];

    float a0 = 0.0f, a1 = 0.0f;
    for (int base = start; base < end; base += 64) {
        int m = end - base;
        if (m > 64) m = 64;
        // each lane owns one edge of this chunk; padded lanes contribute v=0
        iv2 e;
        if (lane < m) {
            e = __builtin_nontemporal_load((const iv2*)(edges_s + base + lane));
        } else {
            e.x = 0; e.y = 0;
        }
        int groups = (m + 15) >> 4;
        for (int g = 0; g < groups; ++g) {
            int j = g << 4;
            float p[16], vv[16];
            #pragma unroll
            for (int k = 0; k < 16; ++k) {
                int d  = __builtin_amdgcn_readlane(e.x, j + k);   // scalar
                vv[k]  = __int_as_float(__builtin_amdgcn_readlane(e.y, j + k));
                const float* row = (d < USER_NUM)
                                 ? (userp + (size_t)d * EMB)
                                 : (itemp + (size_t)(d - USER_NUM) * EMB);
                p[k] = row[lane];   // 16 independent coalesced 256B wave reads
            }
            #pragma unroll
            for (int k = 0; k < 16; k += 2) {
                a0 += vv[k]     * p[k];
                a1 += vv[k + 1] * p[k + 1];
            }
        }
    }

    float a = a0 + a1;
    size_t o = (size_t)wid * EMB + lane;
    if (layer < N_LAYERS - 1) y[o] = a;   // last layer's y is never read
    float t = a * (1.0f / (float)N_LAYERS);
    if (layer == 0) acc[o] = t;           // first layer: pure write
    else            acc[o] += t;
}

// ---------------------------------------------------------------------------

extern "C" void kernel_launch(void* const* d_in, const int* in_sizes, int n_in,
                              void* d_out, int out_size, void* d_ws, size_t ws_size,
                              hipStream_t stream)
{
    const float* user_emb = (const float*)d_in[0];
    const float* item_emb = (const float*)d_in[1];
    const float* edge_val = (const float*)d_in[2];
    const int*   edge_src = (const int*)  d_in[3];
    const int*   edge_dst = (const int*)  d_in[4];
    float* out = (float*)d_out;

    const size_t node_bytes = (size_t)N_NODES * EMB * sizeof(float);  // 76.8 MB

    char* ws = (char*)d_ws;
    float* buf0     = (float*)ws;                 ws += node_bytes;
    float* buf1     = (float*)ws;                 ws += node_bytes;
    int2*  edges_s  = (int2*)ws;                  ws += (size_t)N_EDGES * 8;
    int*   rowptr   = (int*)ws;                   ws += (size_t)(N_NODES + 1) * 4;
    int*   cnt      = (int*)ws;                   ws += (size_t)N_NODES * 4;
    int*   cursor   = (int*)ws;                   ws += (size_t)N_NODES * 4;
    int*   blockSum = (int*)ws;                   ws += SCAN_NB * 4;

    // ---- CSR build ----
    (void)hipMemsetAsync(cnt, 0, (size_t)N_NODES * 4, stream);
    const int e4b = (N_EDGES + 1023) / 1024;        // 4 edges/thread blocks
    hist_kernel <<<e4b, 256, 0, stream>>>(edge_src, cnt);
    scan1_kernel<<<SCAN_NB, 256, 0, stream>>>(cnt, rowptr, blockSum);
    scan2_kernel<<<1, 256, 0, stream>>>(blockSum, SCAN_NB);
    scan3_kernel<<<(N_NODES + 1 + 255) / 256, 256, 0, stream>>>(rowptr, cursor, blockSum);
    scatter_kernel<<<e4b * N_STRIPES, 256, 0, stream>>>(
        edge_src, edge_dst, edge_val, cursor, edges_s);

    // ---- 3 SpMM layers, axpy fused ----
    const int spmm_blocks = (N_NODES * 64 + 255) / 256;   // 1 wave/row
    spmm_csr<<<spmm_blocks, 256, 0, stream>>>(edges_s, rowptr,
                                              user_emb, item_emb,
                                              buf0, out, 0);
    spmm_csr<<<spmm_blocks, 256, 0, stream>>>(edges_s, rowptr,
                                              buf0, buf0 + (size_t)USER_NUM * EMB,
                                              buf1, out, 1);
    spmm_csr<<<spmm_blocks, 256, 0, stream>>>(edges_s, rowptr,
                                              buf1, buf1 + (size_t)USER_NUM * EMB,
                                              buf0, out, 2);
}